// Round 1
// baseline (467.880 us; speedup 1.0000x reference)
//
#include <hip/hip_runtime.h>
#include <math.h>

// Problem constants
#define NMASK 1024
#define HH 256
#define WW 256
#define HW 65536            // H*W
#define OUT_ELEMS 67108864  // NMASK*HW

// ---------------------------------------------------------------------------
// Kernel A: per-mask stats. 1 block per mask, 256 threads, 64 float4/thread.
// Computes hi=count(>1), lo=count(>-1), bbox of (>0).
// ---------------------------------------------------------------------------
__global__ __launch_bounds__(256) void stats_kernel(
    const float* __restrict__ logits, int* __restrict__ stats) {
  const int m = blockIdx.x;
  const int t = threadIdx.x;
  const float4* __restrict__ p = (const float4*)(logits + (size_t)m * HW);

  int hi = 0, lo = 0;
  int miny = HH, maxy = -1, minx = WW, maxx = -1;

  for (int k = 0; k < 64; ++k) {
    const int f = k * 256 + t;          // float4 index within mask [0,16384)
    const float4 v = p[f];
    const int y = f >> 6;               // 64 float4 per row
    const int x0 = (f & 63) << 2;

    const bool p0 = v.x > 0.0f, p1 = v.y > 0.0f, p2 = v.z > 0.0f, p3 = v.w > 0.0f;
    hi += (v.x > 1.0f) + (v.y > 1.0f) + (v.z > 1.0f) + (v.w > 1.0f);
    lo += (v.x > -1.0f) + (v.y > -1.0f) + (v.z > -1.0f) + (v.w > -1.0f);
    if (p0 | p1 | p2 | p3) {
      miny = min(miny, y);
      maxy = max(maxy, y);
      if (p0) { minx = min(minx, x0);     maxx = max(maxx, x0); }
      if (p1) { minx = min(minx, x0 + 1); maxx = max(maxx, x0 + 1); }
      if (p2) { minx = min(minx, x0 + 2); maxx = max(maxx, x0 + 2); }
      if (p3) { minx = min(minx, x0 + 3); maxx = max(maxx, x0 + 3); }
    }
  }

  // wave (64-lane) reduction
  for (int off = 32; off; off >>= 1) {
    hi += __shfl_down(hi, off);
    lo += __shfl_down(lo, off);
    miny = min(miny, __shfl_down(miny, off));
    maxy = max(maxy, __shfl_down(maxy, off));
    minx = min(minx, __shfl_down(minx, off));
    maxx = max(maxx, __shfl_down(maxx, off));
  }

  __shared__ int red[4][6];
  const int wv = t >> 6, ln = t & 63;
  if (ln == 0) {
    red[wv][0] = hi;  red[wv][1] = lo;
    red[wv][2] = miny; red[wv][3] = maxy;
    red[wv][4] = minx; red[wv][5] = maxx;
  }
  __syncthreads();
  if (t == 0) {
    int H2 = 0, L2 = 0, mny = HH, mxy = -1, mnx = WW, mxx = -1;
    for (int w = 0; w < 4; ++w) {
      H2 += red[w][0]; L2 += red[w][1];
      mny = min(mny, red[w][2]); mxy = max(mxy, red[w][3]);
      mnx = min(mnx, red[w][4]); mxx = max(mxx, red[w][5]);
    }
    int* s = stats + m * 8;
    s[0] = H2; s[1] = L2; s[2] = mny; s[3] = mxy; s[4] = mnx; s[5] = mxx;
  }
}

// ---------------------------------------------------------------------------
// Kernel B1a: stability -> valid, score, boxes (orig order). 1 block x 1024.
// ---------------------------------------------------------------------------
__global__ __launch_bounds__(1024) void score_kernel(
    const float* __restrict__ iou_preds, const int* __restrict__ stats,
    float* __restrict__ score, int* __restrict__ validA,
    float* __restrict__ boxf, int* __restrict__ nvalid,
    float* __restrict__ boxes_out) {
  __shared__ int cnt;
  const int i = threadIdx.x;
  if (i == 0) cnt = 0;
  __syncthreads();

  const int* s = stats + i * 8;
  const int hi = s[0], lo = s[1], mny = s[2], mxy = s[3], mnx = s[4], mxx = s[5];
  const float stab = (float)hi / fmaxf((float)lo, 1.0f);
  const float iv = iou_preds[i];
  const bool valid = (iv > 0.88f) && (stab >= 0.95f);

  float bx0, by0, bx1, by1;
  if (mxy < 0) { bx0 = by0 = bx1 = by1 = 0.0f; }
  else { bx0 = (float)mnx; by0 = (float)mny; bx1 = (float)mxx; by1 = (float)mxy; }

  boxf[i * 4 + 0] = bx0; boxf[i * 4 + 1] = by0;
  boxf[i * 4 + 2] = bx1; boxf[i * 4 + 3] = by1;
  boxes_out[i * 4 + 0] = bx0; boxes_out[i * 4 + 1] = by0;
  boxes_out[i * 4 + 2] = bx1; boxes_out[i * 4 + 3] = by1;

  score[i] = valid ? iv : -INFINITY;
  validA[i] = valid ? 1 : 0;
  if (valid) atomicAdd(&cnt, 1);
  __syncthreads();
  if (i == 0) *nvalid = cnt;
}

// ---------------------------------------------------------------------------
// Kernel B1b: rank (stable argsort: score desc, index asc on ties).
// Block i computes rank of mask i and scatters into sorted arrays.
// ---------------------------------------------------------------------------
__global__ __launch_bounds__(256) void rank_kernel(
    const float* __restrict__ score, const int* __restrict__ validA,
    const float* __restrict__ boxf, float* __restrict__ sbox,
    int* __restrict__ sidx, int* __restrict__ svalid) {
  const int i = blockIdx.x;
  const int t = threadIdx.x;
  const float si = score[i];
  int r = 0;
  for (int j = t; j < NMASK; j += 256) {
    const float sj = score[j];
    r += (sj > si) || (sj == si && j < i);
  }
  for (int off = 32; off; off >>= 1) r += __shfl_down(r, off);
  __shared__ int red[4];
  if ((t & 63) == 0) red[t >> 6] = r;
  __syncthreads();
  if (t == 0) {
    const int rank = red[0] + red[1] + red[2] + red[3];
    sidx[rank] = i;
    svalid[rank] = validA[i];
    sbox[rank * 4 + 0] = boxf[i * 4 + 0];
    sbox[rank * 4 + 1] = boxf[i * 4 + 1];
    sbox[rank * 4 + 2] = boxf[i * 4 + 2];
    sbox[rank * 4 + 3] = boxf[i * 4 + 3];
  }
}

// ---------------------------------------------------------------------------
// Kernel B2: suppression bit-matrix over sorted order.
// Row i (block), col j (thread): bit = (iou(i,j) > 0.7) && (j > i).
// Only rows < nvalid are ever read.
// ---------------------------------------------------------------------------
__global__ __launch_bounds__(1024) void iou_kernel(
    const float* __restrict__ sbox, const int* __restrict__ nvalid,
    unsigned long long* __restrict__ rows) {
  const int i = blockIdx.x;
  if (i >= *nvalid) return;
  const int j = threadIdx.x;
  const float ax0 = sbox[i * 4 + 0], ay0 = sbox[i * 4 + 1];
  const float ax1 = sbox[i * 4 + 2], ay1 = sbox[i * 4 + 3];
  const float bx0 = sbox[j * 4 + 0], by0 = sbox[j * 4 + 1];
  const float bx1 = sbox[j * 4 + 2], by1 = sbox[j * 4 + 3];
  const float x0 = fmaxf(ax0, bx0), y0 = fmaxf(ay0, by0);
  const float x1 = fminf(ax1, bx1), y1 = fminf(ay1, by1);
  const float inter = fmaxf(x1 - x0, 0.0f) * fmaxf(y1 - y0, 0.0f);
  const float aa = fmaxf(ax1 - ax0, 0.0f) * fmaxf(ay1 - ay0, 0.0f);
  const float ab = fmaxf(bx1 - bx0, 0.0f) * fmaxf(by1 - by0, 0.0f);
  const float iou = inter / fmaxf(aa + ab - inter, 1e-6f);
  const bool supp = (iou > 0.7f) && (j > i);
  const unsigned long long b = __ballot(supp);
  if ((j & 63) == 0) rows[i * 16 + (j >> 6)] = b;
}

// ---------------------------------------------------------------------------
// Kernel B3: sequential greedy NMS on one wave; keep bits live in 16 lanes.
// Rows prefetched to LDS (first 256 rows; nvalid is expected ~120).
// Writes keep (float 0/1) to d_out and gated[] = keep * iou to ws.
// ---------------------------------------------------------------------------
#define PREF_ROWS 256
__global__ __launch_bounds__(256) void nms_kernel(
    const int* __restrict__ nvalid, const unsigned long long* __restrict__ rows,
    const int* __restrict__ sidx, const int* __restrict__ svalid,
    const float* __restrict__ iou_preds, float* __restrict__ gated,
    float* __restrict__ keep_out) {
  __shared__ unsigned long long srows[PREF_ROWS * 16];
  const int nv = *nvalid;
  const int t = threadIdx.x;
  const int pref = min(nv, PREF_ROWS) * 16;
  for (int k = t; k < pref; k += 256) srows[k] = rows[k];
  __syncthreads();
  if (t >= 64) return;  // single wave from here
  const int lane = t;

  // Build keep0 = svalid (sorted order): lane l holds bits [64l, 64l+64).
  unsigned long long keepword = 0ull;
  for (int c = 0; c < 16; ++c) {
    const int v = svalid[c * 64 + lane];
    const unsigned long long b = __ballot(v != 0);
    if (lane == c) keepword = b;
  }

  // Greedy: invalid entries sort to ranks >= nv, so only nv iterations.
  for (int i = 0; i < nv; ++i) {
    const int w = i >> 6, bit = i & 63;
    const unsigned long long kw = __shfl(keepword, w, 64);  // wave-uniform
    if ((kw >> bit) & 1ull) {
      if (lane < 16) {
        const unsigned long long r =
            (i < PREF_ROWS) ? srows[i * 16 + lane] : rows[i * 16 + lane];
        keepword &= ~r;
      }
    }
  }

  // Scatter results back to original order.
  for (int c = 0; c < 16; ++c) {
    const unsigned long long kw = __shfl(keepword, c, 64);
    const int j = c * 64 + lane;  // sorted position
    const int orig = sidx[j];
    const float kept = ((kw >> lane) & 1ull) ? 1.0f : 0.0f;
    keep_out[orig] = kept;
    gated[orig] = kept * iou_preds[orig];
  }
}

// ---------------------------------------------------------------------------
// Kernel C: out = sigmoid(logits) * gated. Zero-write fast path (no read)
// for gated==0 masks. 16 blocks per mask, 256 thr, 4 float4 per thread.
// ---------------------------------------------------------------------------
__global__ __launch_bounds__(256) void out_kernel(
    const float* __restrict__ logits, const float* __restrict__ gated,
    float* __restrict__ out) {
  const int b = blockIdx.x;
  const int m = b >> 4;
  const float g = gated[m];
  const size_t base4 = (size_t)m * 16384 + (size_t)(b & 15) * 1024;  // float4 units
  const float4* __restrict__ in4 = (const float4*)logits + base4;
  float4* __restrict__ o4 = (float4*)out + base4;
  const int t = threadIdx.x;
  if (g == 0.0f) {
    const float4 z = {0.0f, 0.0f, 0.0f, 0.0f};
    o4[t] = z; o4[t + 256] = z; o4[t + 512] = z; o4[t + 768] = z;
  } else {
#pragma unroll
    for (int k = 0; k < 4; ++k) {
      const float4 v = in4[t + k * 256];
      float4 r;
      r.x = g / (1.0f + __expf(-v.x));
      r.y = g / (1.0f + __expf(-v.y));
      r.z = g / (1.0f + __expf(-v.z));
      r.w = g / (1.0f + __expf(-v.w));
      o4[t + k * 256] = r;
    }
  }
}

// ---------------------------------------------------------------------------
extern "C" void kernel_launch(void* const* d_in, const int* in_sizes, int n_in,
                              void* d_out, int out_size, void* d_ws, size_t ws_size,
                              hipStream_t stream) {
  const float* logits = (const float*)d_in[0];
  const float* iou    = (const float*)d_in[1];

  float* out       = (float*)d_out;
  float* keep_out  = out + OUT_ELEMS;          // 1024 floats
  float* boxes_out = keep_out + NMASK;         // 4096 floats

  // workspace carve (total ~212 KB)
  char* w = (char*)d_ws;
  int*   stats  = (int*)(w);                 // 1024*8 ints  = 32768 B
  float* score  = (float*)(w + 32768);       // 1024 f       -> 36864
  int*   validA = (int*)(w + 36864);         // 1024 i       -> 40960
  float* boxf   = (float*)(w + 40960);       // 4096 f       -> 57344
  int*   nvalid = (int*)(w + 57344);         // 64 B pad     -> 57408
  float* sbox   = (float*)(w + 57408);       // 4096 f       -> 73792
  int*   sidx   = (int*)(w + 73792);         // 1024 i       -> 77888
  int*   svalid = (int*)(w + 77888);         // 1024 i       -> 81984
  float* gated  = (float*)(w + 81984);       // 1024 f       -> 86080
  unsigned long long* rows = (unsigned long long*)(w + 86080);  // 128 KB

  stats_kernel<<<NMASK, 256, 0, stream>>>(logits, stats);
  score_kernel<<<1, 1024, 0, stream>>>(iou, stats, score, validA, boxf, nvalid, boxes_out);
  rank_kernel<<<NMASK, 256, 0, stream>>>(score, validA, boxf, sbox, sidx, svalid);
  iou_kernel<<<NMASK, 1024, 0, stream>>>(sbox, nvalid, rows);
  nms_kernel<<<1, 256, 0, stream>>>(nvalid, rows, sidx, svalid, iou, gated, keep_out);
  out_kernel<<<NMASK * 16, 256, 0, stream>>>(logits, gated, out);
}